// Round 1
// 538.218 us; speedup vs baseline: 1.6862x; 1.6862x over previous
//
#include <hip/hip_runtime.h>

// SGM min-sum message passing, 4 directions, dense 21x21 label context.
// out = sum_d L_d - 3u.
//
// Path A (ws >= 4*NELEM floats; +8 planes for ewT if available):
//   transpose2: uT[b][s][w][h] from u (84 planes) and ewT[b][d][w][h] from
//     ew dirs 2,3 (8 planes) so ALL sweep streams are stride-1.
//   sweep2: 8192 tasks (4 dirs x 2048 lines), 21 lanes/task, 3 tasks/wave.
//     Per-step all-to-all of 21 L values via padded LDS row (wave-sync).
//     Stores: ALL dirs label-major  base[(b*21+s)*512^2 + p*512 + t]:
//       dir0 -> out (raw L);  dir1 -> l1 (L-u);
//       dir2/3 -> l2t/l3t (L-u) which are TRANSPOSED planes [b][s][w][h].
//     Stores staged in LDS 32-step windows ([21][33] padded) and flushed as
//     full 128-B-line wave stores (2 rows x 32 floats per instr) -- kills the
//     write-allocate fetch + partial-line writeback that dominated R5's
//     FETCH=932MB / WRITE=703MB.
//   finish: out += l1 + T(l2t) + T(l3t) via 32x33 LDS tiles (coalesced,
//     full-line; u not needed since dirs 1-3 stored L-u).
// Path B fallback (small ws): sequential no-scratch kernels (unchanged).

#define DLBL 21
#define SP 512
#define NB 4
#define SPSP ((long)SP * SP)
#define NELEM ((long)NB * DLBL * SP * SP)   // 22,020,096 floats

// ---------------- transpose: u planes (0..83) + ew dirs 2,3 (84..91) -------
__global__ __launch_bounds__(256)
void transpose2_kernel(const float* __restrict__ u, const float* __restrict__ ew,
                       float* __restrict__ uT, float* __restrict__ ewT)
{
    __shared__ float tile[32][33];
    const int plane = blockIdx.z;
    const float* src;
    float* dst;
    if (plane < NB * DLBL) {
        src = u  + (long)plane * SPSP;
        dst = uT + (long)plane * SPSP;
    } else {
        const int q = plane - NB * DLBL;            // q = b*2 + (dir-2)
        src = ew  + (long)((q >> 1) * 4 + 2 + (q & 1)) * SPSP;
        dst = ewT + (long)q * SPSP;
    }
    const int x0 = blockIdx.x * 32, y0 = blockIdx.y * 32;
    const int tx = threadIdx.x & 31, ty = threadIdx.x >> 5;  // 32 x 8
#pragma unroll
    for (int j = 0; j < 4; ++j)
        tile[ty + 8 * j][tx] = src[(long)(y0 + ty + 8 * j) * SP + (x0 + tx)];
    __syncthreads();
#pragma unroll
    for (int j = 0; j < 4; ++j)
        dst[(long)(x0 + ty + 8 * j) * SP + (y0 + tx)] = tile[tx][ty + 8 * j];
}

// ---------------- main sweep (Path A) ----------------
template<bool EWT>
__global__ __launch_bounds__(64)
void sweep2(const float* __restrict__ unary, const float* __restrict__ ew,
            const float* __restrict__ Vmat, const float* __restrict__ uT,
            const float* __restrict__ ewT,
            float* __restrict__ out, float* __restrict__ l1,
            float* __restrict__ l2t, float* __restrict__ l3t)
{
    __shared__ float xch[4][24];
    __shared__ float stage[4][693];      // [group][s*33 + (t&31)], +1 pad/row
    const int lane = threadIdx.x;
    const int g    = lane / DLBL;              // 0..2 (3 = idle lane 63)
    const int s    = lane - g * DLBL;
    int taskId = blockIdx.x * 3 + (g < 3 ? g : 0);
    if (taskId >= 8192) taskId = 8191;

    const int dir  = taskId >> 11;
    const int line = taskId & 2047;
    const int b    = line >> 9;
    const int p    = line & (SP - 1);          // h for axis 0, w for axis 1
    const int axis = dir >> 1;
    const int rev  = dir & 1;
    const float usub = (dir == 0) ? 0.0f : 1.0f;   // dirs 1-3 store L-u

    float Vc[DLBL];
#pragma unroll
    for (int j = 0; j < DLBL; ++j) Vc[j] = Vmat[j * DLBL + s];

    // u stream: contiguous along scan axis for every direction
    const float* ub = (axis ? uT : unary) + (long)(b * DLBL + s) * SPSP + (long)p * SP;

    // w stream: stride-1 everywhere when ewT present
    const float* wb;
    if constexpr (EWT) {
        wb = axis ? (ewT + (long)(b * 2 + (dir - 2)) * SPSP + (long)p * SP)
                  : (ew  + (long)(b * 4 + dir)       * SPSP + (long)p * SP);
    } else {
        wb = ew + (long)(b * 4 + dir) * SPSP + (axis ? (long)p : (long)p * SP);
    }
    const long wstride = axis ? SP : 1;            // only used when !EWT

    const int dstep = rev ? -1 : 1;
    int tg = rev ? (SP / 4 - 1) : 0;
    const float4* ub4 = (const float4*)ub;
    float4 uv = ub4[tg];
    float wv[4];
    if constexpr (EWT) {
        const float4 w4 = ((const float4*)wb)[tg];
        wv[0] = w4.x; wv[1] = w4.y; wv[2] = w4.z; wv[3] = w4.w;
    } else {
#pragma unroll
        for (int k = 0; k < 4; ++k) wv[k] = wb[(long)(tg * 4 + k) * wstride];
    }
    float cur = 0.0f;
    const int stbase = s * 33;

    for (int gi = 0; gi < SP / 4; ++gi) {
        const int tgn = (gi + 1 < SP / 4) ? tg + dstep : tg;
        const float4 uvN = ub4[tgn];                    // prefetch next group
        float wvN[4];
        if constexpr (EWT) {
            const float4 w4 = ((const float4*)wb)[tgn];
            wvN[0] = w4.x; wvN[1] = w4.y; wvN[2] = w4.z; wvN[3] = w4.w;
        } else {
#pragma unroll
            for (int k = 0; k < 4; ++k) wvN[k] = wb[(long)(tgn * 4 + k) * wstride];
        }
        const float ua[4] = {uv.x, uv.y, uv.z, uv.w};
#pragma unroll
        for (int j = 0; j < 4; ++j) {
            const int   jc  = rev ? 3 - j : j;
            const float u_c = ua[jc];
            const float w_c = wv[jc];
            const int   t   = tg * 4 + jc;
            if (gi == 0 && j == 0) {
                cur = u_c;                              // border: L = u
            } else {
                xch[g][s] = cur;
                __builtin_amdgcn_wave_barrier();
                float Lp[24];
#pragma unroll
                for (int q = 0; q < 6; ++q)
                    ((float4*)Lp)[q] = ((const float4*)(&xch[g][0]))[q];
                __builtin_amdgcn_wave_barrier();

                float c[DLBL];
#pragma unroll
                for (int jj = 0; jj < DLBL; ++jj) c[jj] = fmaf(w_c, Vc[jj], Lp[jj]);
                float m7[7];
#pragma unroll
                for (int k = 0; k < 7; ++k)
                    m7[k] = fminf(fminf(c[3 * k], c[3 * k + 1]), c[3 * k + 2]);
                const float ma = fminf(fminf(m7[0], m7[1]), m7[2]);
                const float mb = fminf(fminf(m7[3], m7[4]), m7[5]);
                cur = u_c + fminf(fminf(ma, mb), m7[6]);
            }
            // stage into 32-step LDS window (slot = t&31; window base % 32 == 0)
            stage[g][stbase + (t & 31)] = fmaf(-usub, u_c, cur);
        }
        uv = uvN;
#pragma unroll
        for (int k = 0; k < 4; ++k) wv[k] = wvN[k];
        tg = tgn;

        if ((gi & 7) == 7) {                 // window complete: flush 32 cols
            __builtin_amdgcn_wave_barrier();
            const int row = lane >> 5, col = lane & 31;
            for (int gg = 0; gg < 3; ++gg) {
                const int tid = blockIdx.x * 3 + gg;
                if (tid >= 8192) break;
                const int d_ = tid >> 11;
                const int ln = tid & 2047;
                const int bb = ln >> 9;
                const int pp = ln & (SP - 1);
                const int w0 = (d_ & 1) ? (508 - 4 * gi) : (4 * gi - 28);
                float* dst = (d_ == 0) ? out : (d_ == 1) ? l1
                           : (d_ == 2) ? l2t : l3t;
                float* bp  = dst + (long)(bb * DLBL) * SPSP + (long)pp * SP
                                 + w0 + (long)row * SPSP;
                // 2 full 128-B rows per store instr (lanes 0-31 / 32-63)
#pragma unroll
                for (int r2 = 0; r2 < 11; ++r2) {
                    const int rr = 2 * r2 + row;
                    if (rr < DLBL) bp[col] = stage[gg][rr * 33 + col];
                    bp += 2 * SPSP;
                }
            }
            __builtin_amdgcn_wave_barrier();
        }
    }
}

// ---------------- finish: out += l1 + T(l2t) + T(l3t) ----------------
__global__ __launch_bounds__(256)
void finish_kernel(const float* __restrict__ l1, const float* __restrict__ l2t,
                   const float* __restrict__ l3t, float* __restrict__ out)
{
    __shared__ float t2[32][33], t3[32][33];
    const long pb = (long)blockIdx.z * SPSP;
    const int x0 = blockIdx.x * 32, y0 = blockIdx.y * 32;
    const int tx = threadIdx.x & 31, ty = threadIdx.x >> 5;
#pragma unroll
    for (int j = 0; j < 4; ++j) {
        const long o = pb + (long)(x0 + ty + 8 * j) * SP + (y0 + tx);
        t2[ty + 8 * j][tx] = l2t[o];
        t3[ty + 8 * j][tx] = l3t[o];
    }
    __syncthreads();
#pragma unroll
    for (int j = 0; j < 4; ++j) {
        const long o = pb + (long)(y0 + ty + 8 * j) * SP + (x0 + tx);
        out[o] = out[o] + l1[o] + t2[tx][ty + 8 * j] + t3[tx][ty + 8 * j];
    }
}

// ---------------- fallback (Path B): no-scratch sequential sweeps ----------
template<int MODE>   // 1: dir0 store L to out; 2: out += L - u
__global__ __launch_bounds__(64)
void sweep_fb(const float* __restrict__ unary, const float* __restrict__ ew,
              const float* __restrict__ Vmat, float* __restrict__ out,
              int taskBase)
{
    __shared__ float xch[4][24];
    const int lane = threadIdx.x;
    const int g    = lane / DLBL;
    const int s    = lane - g * DLBL;
    int local = blockIdx.x * 3 + (g < 3 ? g : 0);
    const bool valid = (g < 3) && (local < 2048);
    if (local >= 2048) local = 2047;
    const int taskId = taskBase + local;
    const int dir  = taskId >> 11;
    const int line = taskId & 2047;
    const int b = line >> 9, p = line & (SP - 1);
    const int axis = dir >> 1, rev = dir & 1;

    float Vc[DLBL];
#pragma unroll
    for (int j = 0; j < DLBL; ++j) Vc[j] = Vmat[j * DLBL + s];

    const long ustep = axis ? SP : 1;
    const long ubase = (long)(b * DLBL + s) * SPSP + (axis ? (long)p : (long)p * SP);
    const long wbase = (long)(b * 4 + dir) * SPSP + (axis ? (long)p : (long)p * SP);
    const long uoff  = rev ? -ustep : ustep;
    const long ust   = rev ? (long)(SP - 1) * ustep : 0;

    const float* up = unary + ubase + ust;
    const float* wp = ew    + wbase + ust;
    float*       op = out   + ubase + ust;

    float cur = up[0];
    if (valid && MODE == 1) *op = cur;

    float ub0 = up[uoff], ub1 = up[2*uoff], ub2 = up[3*uoff], ub3 = up[4*uoff];
    float wb0 = wp[uoff], wb1 = wp[2*uoff], wb2 = wp[3*uoff], wb3 = wp[4*uoff];
    float ob0 = 0, ob1 = 0, ob2 = 0, ob3 = 0;
    if (MODE == 2) { ob0 = op[uoff]; ob1 = op[2*uoff]; ob2 = op[3*uoff]; ob3 = op[4*uoff]; }
    const float* upf = up + 4 * uoff;
    const float* wpf = wp + 4 * uoff;
    const float* opf = op + 4 * uoff;

    for (int t = 1; t < SP; ++t) {
        const float u_c = ub0, w_c = wb0, o_c = ob0;
        ub0 = ub1; ub1 = ub2; ub2 = ub3;
        wb0 = wb1; wb1 = wb2; wb2 = wb3;
        if (MODE == 2) { ob0 = ob1; ob1 = ob2; ob2 = ob3; }
        const bool adv = (t + 4) < SP;
        upf += adv ? uoff : 0; wpf += adv ? uoff : 0;
        ub3 = *upf; wb3 = *wpf;
        if (MODE == 2) { opf += adv ? uoff : 0; ob3 = *opf; }

        xch[g][s] = cur;
        __builtin_amdgcn_wave_barrier();
        float Lp[24];
#pragma unroll
        for (int q = 0; q < 6; ++q)
            ((float4*)Lp)[q] = ((const float4*)(&xch[g][0]))[q];
        __builtin_amdgcn_wave_barrier();

        float c[DLBL];
#pragma unroll
        for (int j = 0; j < DLBL; ++j) c[j] = fmaf(w_c, Vc[j], Lp[j]);
        float m7[7];
#pragma unroll
        for (int k = 0; k < 7; ++k)
            m7[k] = fminf(fminf(c[3*k], c[3*k+1]), c[3*k+2]);
        const float ma = fminf(fminf(m7[0], m7[1]), m7[2]);
        const float mb = fminf(fminf(m7[3], m7[4]), m7[5]);
        cur = u_c + fminf(fminf(ma, mb), m7[6]);

        op += uoff;
        if (valid) *op = (MODE == 2) ? (o_c + cur - u_c) : cur;
    }
}

extern "C" void kernel_launch(void* const* d_in, const int* in_sizes, int n_in,
                              void* d_out, int out_size, void* d_ws, size_t ws_size,
                              hipStream_t stream) {
    const float* unary = (const float*)d_in[0];   // (4,1,21,512,512) f32
    const float* ew    = (const float*)d_in[1];   // (4,4,512,512)   f32
    const float* Vmat  = (const float*)d_in[2];   // (21,21)         f32
    float* o = (float*)d_out;

    const size_t needA  = (size_t)(4 * NELEM) * sizeof(float);   // 352,321,536 B
    const size_t needAe = needA + (size_t)(8 * SPSP) * sizeof(float); // + ewT

    if (ws_size >= needA) {
        float* uT  = (float*)d_ws;
        float* l1  = uT + NELEM;
        float* l2t = l1 + NELEM;
        float* l3t = l2t + NELEM;
        float* ewT = l3t + NELEM;                 // only touched if needAe fits
        const bool useE = (ws_size >= needAe);

        dim3 tg(16, 16, useE ? (NB * DLBL + 8) : (NB * DLBL));
        transpose2_kernel<<<tg, 256, 0, stream>>>(unary, ew, uT, ewT);

        const int grid = (8192 + 2) / 3;          // 2731
        if (useE)
            sweep2<true><<<grid, 64, 0, stream>>>(unary, ew, Vmat, uT, ewT,
                                                  o, l1, l2t, l3t);
        else
            sweep2<false><<<grid, 64, 0, stream>>>(unary, ew, Vmat, uT, ewT,
                                                   o, l1, l2t, l3t);

        finish_kernel<<<dim3(16, 16, NB * DLBL), 256, 0, stream>>>(l1, l2t, l3t, o);
    } else {
        const int grid = (2048 + 2) / 3;          // 683
        sweep_fb<1><<<grid, 64, 0, stream>>>(unary, ew, Vmat, o, 0);
        for (int d = 1; d < 4; ++d)
            sweep_fb<2><<<grid, 64, 0, stream>>>(unary, ew, Vmat, o, d * 2048);
    }
}

// Round 2
// 536.438 us; speedup vs baseline: 1.6918x; 1.0033x over previous
//
#include <hip/hip_runtime.h>

// SGM min-sum message passing, 4 directions, dense 21x21 label context.
// out = sum_d L_d - 3u.
//
// Path A (ws >= 4*NELEM floats; +8 planes for ewT if available):
//   transpose2: uT[b][s][w][h] from u (84 planes) and ewT[b][d][w][h] from
//     ew dirs 2,3 (8 planes) so ALL sweep streams are stride-1.
//   sweep3 (EWT only): 8192 tasks (4 dirs x 2048 lines), 21 lanes/task,
//     3 tasks/wave. Streams consumed in 16-step blocks (64 B/lane bursts,
//     4x float4) with register double-buffering (uA/uB/wA/wB) -- full-sector
//     consumption kills the L2 stream-front thrash that inflated R1's
//     FETCH to 654 MB, and gives ~4000-cycle prefetch distance.
//     Per-step all-to-all of 21 L values via padded LDS row (wave-sync).
//     Stores: ALL dirs label-major base[(b*21+s)*512^2 + p*512 + t]:
//       dir0 -> out (raw L); dir1 -> l1 (L-u); dir2/3 -> l2t/l3t (L-u,
//       TRANSPOSED planes). Staged in LDS 32-step windows, flushed as full
//       128-B-line wave stores (WRITE_SIZE exact 352 MB, verified R1).
//   finish: out += l1 + T(l2t) + T(l3t) via 32x33 LDS tiles.
// Path B fallback (small ws): sequential no-scratch kernels (unchanged).

#define DLBL 21
#define SP 512
#define NB 4
#define SPSP ((long)SP * SP)
#define NELEM ((long)NB * DLBL * SP * SP)   // 22,020,096 floats

// ---------------- transpose: u planes (0..83) + ew dirs 2,3 (84..91) -------
__global__ __launch_bounds__(256)
void transpose2_kernel(const float* __restrict__ u, const float* __restrict__ ew,
                       float* __restrict__ uT, float* __restrict__ ewT)
{
    __shared__ float tile[32][33];
    const int plane = blockIdx.z;
    const float* src;
    float* dst;
    if (plane < NB * DLBL) {
        src = u  + (long)plane * SPSP;
        dst = uT + (long)plane * SPSP;
    } else {
        const int q = plane - NB * DLBL;            // q = b*2 + (dir-2)
        src = ew  + (long)((q >> 1) * 4 + 2 + (q & 1)) * SPSP;
        dst = ewT + (long)q * SPSP;
    }
    const int x0 = blockIdx.x * 32, y0 = blockIdx.y * 32;
    const int tx = threadIdx.x & 31, ty = threadIdx.x >> 5;  // 32 x 8
#pragma unroll
    for (int j = 0; j < 4; ++j)
        tile[ty + 8 * j][tx] = src[(long)(y0 + ty + 8 * j) * SP + (x0 + tx)];
    __syncthreads();
#pragma unroll
    for (int j = 0; j < 4; ++j)
        dst[(long)(x0 + ty + 8 * j) * SP + (y0 + tx)] = tile[tx][ty + 8 * j];
}

// ---------------- main sweep (Path A, blocked streams) ----------------
__global__ __launch_bounds__(64, 3)
void sweep3(const float* __restrict__ unary, const float* __restrict__ ew,
            const float* __restrict__ Vmat, const float* __restrict__ uT,
            const float* __restrict__ ewT,
            float* __restrict__ out, float* __restrict__ l1,
            float* __restrict__ l2t, float* __restrict__ l3t)
{
    __shared__ float xch[4][24];
    __shared__ float stage[4][693];      // [group][s*33 + (t&31)], +1 pad/row
    const int lane = threadIdx.x;
    const int g    = lane / DLBL;              // 0..2 (3 = idle lane 63)
    const int s    = lane - g * DLBL;
    int taskId = blockIdx.x * 3 + (g < 3 ? g : 0);
    if (taskId >= 8192) taskId = 8191;

    const int dir  = taskId >> 11;
    const int line = taskId & 2047;
    const int b    = line >> 9;
    const int p    = line & (SP - 1);          // h for axis 0, w for axis 1
    const int axis = dir >> 1;
    const int rev  = dir & 1;
    const float usub = (dir == 0) ? 0.0f : 1.0f;   // dirs 1-3 store L-u

    float Vc[DLBL];
#pragma unroll
    for (int j = 0; j < DLBL; ++j) Vc[j] = Vmat[j * DLBL + s];

    const float4* ub4 = (const float4*)((axis ? uT : unary)
                        + (long)(b * DLBL + s) * SPSP + (long)p * SP);
    const float4* wb4 = (const float4*)((axis
                        ? (ewT + (long)(b * 2 + (dir - 2)) * SPSP)
                        : (ew  + (long)(b * 4 + dir) * SPSP)) + (long)p * SP);

    const int frow = lane >> 5, fcol = lane & 31;
    const int stbase = s * 33;

    float4 uA[4], uB[4], wA[4], wB[4];
    float cur = 0.0f;

#define QIDX(bi, k) (rev ? (127 - 4 * (bi) - (k)) : (4 * (bi) + (k)))

#define LOADBLK(bi, U, W) do {                                              \
    _Pragma("unroll")                                                       \
    for (int k = 0; k < 4; ++k) {                                           \
        const int q_ = QIDX(bi, k);                                         \
        U[k] = ub4[q_]; W[k] = wb4[q_];                                     \
    } } while (0)

#define PROCESS(bi, U, W, FIRST) do {                                       \
    _Pragma("unroll")                                                       \
    for (int k = 0; k < 4; ++k) {                                           \
        const float ua_[4] = {U[k].x, U[k].y, U[k].z, U[k].w};              \
        const float wa_[4] = {W[k].x, W[k].y, W[k].z, W[k].w};              \
        const int q_ = QIDX(bi, k);                                         \
        _Pragma("unroll")                                                   \
        for (int j = 0; j < 4; ++j) {                                       \
            const int   jc  = rev ? 3 - j : j;                              \
            const float u_c = ua_[jc];                                      \
            const float w_c = wa_[jc];                                      \
            const int   t   = q_ * 4 + jc;                                  \
            xch[g][s] = cur;                                                \
            __builtin_amdgcn_wave_barrier();                                \
            float Lp[24];                                                   \
            _Pragma("unroll")                                               \
            for (int qq = 0; qq < 6; ++qq)                                  \
                ((float4*)Lp)[qq] = ((const float4*)(&xch[g][0]))[qq];      \
            __builtin_amdgcn_wave_barrier();                                \
            float c[DLBL];                                                  \
            _Pragma("unroll")                                               \
            for (int jj = 0; jj < DLBL; ++jj)                               \
                c[jj] = fmaf(w_c, Vc[jj], Lp[jj]);                          \
            float m7[7];                                                    \
            _Pragma("unroll")                                               \
            for (int kk = 0; kk < 7; ++kk)                                  \
                m7[kk] = fminf(fminf(c[3*kk], c[3*kk+1]), c[3*kk+2]);       \
            const float ma = fminf(fminf(m7[0], m7[1]), m7[2]);             \
            const float mb = fminf(fminf(m7[3], m7[4]), m7[5]);             \
            const float nv = u_c + fminf(fminf(ma, mb), m7[6]);             \
            cur = ((FIRST) && k == 0 && j == 0) ? u_c : nv;                 \
            stage[g][stbase + (t & 31)] = fmaf(-usub, u_c, cur);            \
        }                                                                   \
    } } while (0)

#define FLUSH(bi) do {                                                      \
    __builtin_amdgcn_wave_barrier();                                        \
    for (int gg = 0; gg < 3; ++gg) {                                        \
        const int tid = blockIdx.x * 3 + gg;                                \
        if (tid >= 8192) break;                                             \
        const int d_ = tid >> 11;                                           \
        const int ln = tid & 2047;                                          \
        const int bb = ln >> 9;                                             \
        const int pp = ln & (SP - 1);                                       \
        const int w0 = (d_ & 1) ? (496 - 16 * (bi)) : (16 * (bi) - 16);     \
        float* dst = (d_ == 0) ? out : (d_ == 1) ? l1                       \
                   : (d_ == 2) ? l2t : l3t;                                 \
        float* bp = dst + (long)(bb * DLBL) * SPSP + (long)pp * SP + w0     \
                        + (long)frow * SPSP;                                \
        _Pragma("unroll")                                                   \
        for (int r2 = 0; r2 < 11; ++r2) {                                   \
            const int rr = 2 * r2 + frow;                                   \
            if (rr < DLBL) bp[fcol] = stage[gg][rr * 33 + fcol];            \
            bp += 2 * SPSP;                                                 \
        }                                                                   \
    }                                                                       \
    __builtin_amdgcn_wave_barrier();                                        \
} while (0)

    LOADBLK(0, uA, wA);
    for (int m = 0; m < 16; ++m) {
        LOADBLK(2 * m + 1, uB, wB);        // prefetch odd block
        PROCESS(2 * m, uA, wA, (m == 0));
        if (m < 15) LOADBLK(2 * m + 2, uA, wA);   // prefetch next even block
        PROCESS(2 * m + 1, uB, wB, false);
        FLUSH(2 * m + 1);                  // 32-step window complete
    }

#undef QIDX
#undef LOADBLK
#undef PROCESS
#undef FLUSH
}

// ---------------- legacy sweep (Path A without ewT) ----------------
__global__ __launch_bounds__(64)
void sweep2(const float* __restrict__ unary, const float* __restrict__ ew,
            const float* __restrict__ Vmat, const float* __restrict__ uT,
            float* __restrict__ out, float* __restrict__ l1,
            float* __restrict__ l2t, float* __restrict__ l3t)
{
    __shared__ float xch[4][24];
    __shared__ float stage[4][693];
    const int lane = threadIdx.x;
    const int g    = lane / DLBL;
    const int s    = lane - g * DLBL;
    int taskId = blockIdx.x * 3 + (g < 3 ? g : 0);
    if (taskId >= 8192) taskId = 8191;

    const int dir  = taskId >> 11;
    const int line = taskId & 2047;
    const int b    = line >> 9;
    const int p    = line & (SP - 1);
    const int axis = dir >> 1;
    const int rev  = dir & 1;
    const float usub = (dir == 0) ? 0.0f : 1.0f;

    float Vc[DLBL];
#pragma unroll
    for (int j = 0; j < DLBL; ++j) Vc[j] = Vmat[j * DLBL + s];

    const float* ub = (axis ? uT : unary) + (long)(b * DLBL + s) * SPSP + (long)p * SP;
    const long  wstride = axis ? SP : 1;
    const float* wb = ew + (long)(b * 4 + dir) * SPSP + (axis ? (long)p : (long)p * SP);

    const int dstep = rev ? -1 : 1;
    int tg = rev ? (SP / 4 - 1) : 0;
    const float4* ub4 = (const float4*)ub;
    float4 uv = ub4[tg];
    float wv[4];
#pragma unroll
    for (int k = 0; k < 4; ++k) wv[k] = wb[(long)(tg * 4 + k) * wstride];
    float cur = 0.0f;
    const int stbase = s * 33;

    for (int gi = 0; gi < SP / 4; ++gi) {
        const int tgn = (gi + 1 < SP / 4) ? tg + dstep : tg;
        const float4 uvN = ub4[tgn];
        float wvN[4];
#pragma unroll
        for (int k = 0; k < 4; ++k) wvN[k] = wb[(long)(tgn * 4 + k) * wstride];
        const float ua[4] = {uv.x, uv.y, uv.z, uv.w};
#pragma unroll
        for (int j = 0; j < 4; ++j) {
            const int   jc  = rev ? 3 - j : j;
            const float u_c = ua[jc];
            const float w_c = wv[jc];
            const int   t   = tg * 4 + jc;
            if (gi == 0 && j == 0) {
                cur = u_c;
            } else {
                xch[g][s] = cur;
                __builtin_amdgcn_wave_barrier();
                float Lp[24];
#pragma unroll
                for (int q = 0; q < 6; ++q)
                    ((float4*)Lp)[q] = ((const float4*)(&xch[g][0]))[q];
                __builtin_amdgcn_wave_barrier();

                float c[DLBL];
#pragma unroll
                for (int jj = 0; jj < DLBL; ++jj) c[jj] = fmaf(w_c, Vc[jj], Lp[jj]);
                float m7[7];
#pragma unroll
                for (int k = 0; k < 7; ++k)
                    m7[k] = fminf(fminf(c[3 * k], c[3 * k + 1]), c[3 * k + 2]);
                const float ma = fminf(fminf(m7[0], m7[1]), m7[2]);
                const float mb = fminf(fminf(m7[3], m7[4]), m7[5]);
                cur = u_c + fminf(fminf(ma, mb), m7[6]);
            }
            stage[g][stbase + (t & 31)] = fmaf(-usub, u_c, cur);
        }
        uv = uvN;
#pragma unroll
        for (int k = 0; k < 4; ++k) wv[k] = wvN[k];
        tg = tgn;

        if ((gi & 7) == 7) {
            __builtin_amdgcn_wave_barrier();
            const int row = lane >> 5, col = lane & 31;
            for (int gg = 0; gg < 3; ++gg) {
                const int tid = blockIdx.x * 3 + gg;
                if (tid >= 8192) break;
                const int d_ = tid >> 11;
                const int ln = tid & 2047;
                const int bb = ln >> 9;
                const int pp = ln & (SP - 1);
                const int w0 = (d_ & 1) ? (508 - 4 * gi) : (4 * gi - 28);
                float* dst = (d_ == 0) ? out : (d_ == 1) ? l1
                           : (d_ == 2) ? l2t : l3t;
                float* bp  = dst + (long)(bb * DLBL) * SPSP + (long)pp * SP
                                 + w0 + (long)row * SPSP;
#pragma unroll
                for (int r2 = 0; r2 < 11; ++r2) {
                    const int rr = 2 * r2 + row;
                    if (rr < DLBL) bp[col] = stage[gg][rr * 33 + col];
                    bp += 2 * SPSP;
                }
            }
            __builtin_amdgcn_wave_barrier();
        }
    }
}

// ---------------- finish: out += l1 + T(l2t) + T(l3t) ----------------
__global__ __launch_bounds__(256)
void finish_kernel(const float* __restrict__ l1, const float* __restrict__ l2t,
                   const float* __restrict__ l3t, float* __restrict__ out)
{
    __shared__ float t2[32][33], t3[32][33];
    const long pb = (long)blockIdx.z * SPSP;
    const int x0 = blockIdx.x * 32, y0 = blockIdx.y * 32;
    const int tx = threadIdx.x & 31, ty = threadIdx.x >> 5;
#pragma unroll
    for (int j = 0; j < 4; ++j) {
        const long o = pb + (long)(x0 + ty + 8 * j) * SP + (y0 + tx);
        t2[ty + 8 * j][tx] = l2t[o];
        t3[ty + 8 * j][tx] = l3t[o];
    }
    __syncthreads();
#pragma unroll
    for (int j = 0; j < 4; ++j) {
        const long o = pb + (long)(y0 + ty + 8 * j) * SP + (x0 + tx);
        out[o] = out[o] + l1[o] + t2[tx][ty + 8 * j] + t3[tx][ty + 8 * j];
    }
}

// ---------------- fallback (Path B): no-scratch sequential sweeps ----------
template<int MODE>   // 1: dir0 store L to out; 2: out += L - u
__global__ __launch_bounds__(64)
void sweep_fb(const float* __restrict__ unary, const float* __restrict__ ew,
              const float* __restrict__ Vmat, float* __restrict__ out,
              int taskBase)
{
    __shared__ float xch[4][24];
    const int lane = threadIdx.x;
    const int g    = lane / DLBL;
    const int s    = lane - g * DLBL;
    int local = blockIdx.x * 3 + (g < 3 ? g : 0);
    const bool valid = (g < 3) && (local < 2048);
    if (local >= 2048) local = 2047;
    const int taskId = taskBase + local;
    const int dir  = taskId >> 11;
    const int line = taskId & 2047;
    const int b = line >> 9, p = line & (SP - 1);
    const int axis = dir >> 1, rev = dir & 1;

    float Vc[DLBL];
#pragma unroll
    for (int j = 0; j < DLBL; ++j) Vc[j] = Vmat[j * DLBL + s];

    const long ustep = axis ? SP : 1;
    const long ubase = (long)(b * DLBL + s) * SPSP + (axis ? (long)p : (long)p * SP);
    const long wbase = (long)(b * 4 + dir) * SPSP + (axis ? (long)p : (long)p * SP);
    const long uoff  = rev ? -ustep : ustep;
    const long ust   = rev ? (long)(SP - 1) * ustep : 0;

    const float* up = unary + ubase + ust;
    const float* wp = ew    + wbase + ust;
    float*       op = out   + ubase + ust;

    float cur = up[0];
    if (valid && MODE == 1) *op = cur;

    float ub0 = up[uoff], ub1 = up[2*uoff], ub2 = up[3*uoff], ub3 = up[4*uoff];
    float wb0 = wp[uoff], wb1 = wp[2*uoff], wb2 = wp[3*uoff], wb3 = wp[4*uoff];
    float ob0 = 0, ob1 = 0, ob2 = 0, ob3 = 0;
    if (MODE == 2) { ob0 = op[uoff]; ob1 = op[2*uoff]; ob2 = op[3*uoff]; ob3 = op[4*uoff]; }
    const float* upf = up + 4 * uoff;
    const float* wpf = wp + 4 * uoff;
    const float* opf = op + 4 * uoff;

    for (int t = 1; t < SP; ++t) {
        const float u_c = ub0, w_c = wb0, o_c = ob0;
        ub0 = ub1; ub1 = ub2; ub2 = ub3;
        wb0 = wb1; wb1 = wb2; wb2 = wb3;
        if (MODE == 2) { ob0 = ob1; ob1 = ob2; ob2 = ob3; }
        const bool adv = (t + 4) < SP;
        upf += adv ? uoff : 0; wpf += adv ? uoff : 0;
        ub3 = *upf; wb3 = *wpf;
        if (MODE == 2) { opf += adv ? uoff : 0; ob3 = *opf; }

        xch[g][s] = cur;
        __builtin_amdgcn_wave_barrier();
        float Lp[24];
#pragma unroll
        for (int q = 0; q < 6; ++q)
            ((float4*)Lp)[q] = ((const float4*)(&xch[g][0]))[q];
        __builtin_amdgcn_wave_barrier();

        float c[DLBL];
#pragma unroll
        for (int j = 0; j < DLBL; ++j) c[j] = fmaf(w_c, Vc[j], Lp[j]);
        float m7[7];
#pragma unroll
        for (int k = 0; k < 7; ++k)
            m7[k] = fminf(fminf(c[3*k], c[3*k+1]), c[3*k+2]);
        const float ma = fminf(fminf(m7[0], m7[1]), m7[2]);
        const float mb = fminf(fminf(m7[3], m7[4]), m7[5]);
        cur = u_c + fminf(fminf(ma, mb), m7[6]);

        op += uoff;
        if (valid) *op = (MODE == 2) ? (o_c + cur - u_c) : cur;
    }
}

extern "C" void kernel_launch(void* const* d_in, const int* in_sizes, int n_in,
                              void* d_out, int out_size, void* d_ws, size_t ws_size,
                              hipStream_t stream) {
    const float* unary = (const float*)d_in[0];   // (4,1,21,512,512) f32
    const float* ew    = (const float*)d_in[1];   // (4,4,512,512)   f32
    const float* Vmat  = (const float*)d_in[2];   // (21,21)         f32
    float* o = (float*)d_out;

    const size_t needA  = (size_t)(4 * NELEM) * sizeof(float);   // 352,321,536 B
    const size_t needAe = needA + (size_t)(8 * SPSP) * sizeof(float); // + ewT

    if (ws_size >= needA) {
        float* uT  = (float*)d_ws;
        float* l1  = uT + NELEM;
        float* l2t = l1 + NELEM;
        float* l3t = l2t + NELEM;
        float* ewT = l3t + NELEM;                 // only touched if needAe fits
        const bool useE = (ws_size >= needAe);

        dim3 tg(16, 16, useE ? (NB * DLBL + 8) : (NB * DLBL));
        transpose2_kernel<<<tg, 256, 0, stream>>>(unary, ew, uT, ewT);

        const int grid = (8192 + 2) / 3;          // 2731
        if (useE)
            sweep3<<<grid, 64, 0, stream>>>(unary, ew, Vmat, uT, ewT,
                                            o, l1, l2t, l3t);
        else
            sweep2<<<grid, 64, 0, stream>>>(unary, ew, Vmat, uT,
                                            o, l1, l2t, l3t);

        finish_kernel<<<dim3(16, 16, NB * DLBL), 256, 0, stream>>>(l1, l2t, l3t, o);
    } else {
        const int grid = (2048 + 2) / 3;          // 683
        sweep_fb<1><<<grid, 64, 0, stream>>>(unary, ew, Vmat, o, 0);
        for (int d = 1; d < 4; ++d)
            sweep_fb<2><<<grid, 64, 0, stream>>>(unary, ew, Vmat, o, d * 2048);
    }
}

// Round 3
// 449.003 us; speedup vs baseline: 2.0212x; 1.1947x over previous
//
#include <hip/hip_runtime.h>

// SGM min-sum message passing, 4 directions, dense 21x21 label context.
// out = sum_d L_d - 3u.
//
// Path A (ws >= 4*NELEM floats exactly -- the proven size):
//   transpose2: uT[b][s][w][h] from u (84 planes) AND ewT planes for dirs
//     2,3 OVERLAID into l2t/l3t plane (b*21+20) -- no extra workspace.
//     Overlay is race-free: task (b,p,dir) is the only reader (w row
//     p*512+t) and only writer (s=20 flush row) of those offsets, and the
//     sweep schedule loads every offset (consumed via real data deps)
//     strictly before its flush writes it, in single-wave program order.
//   sweep3: 8192 tasks (4 dirs x 2048 lines), 21 lanes/task, 3 tasks/wave.
//     ALL streams stride-1; consumed in 16-step blocks (64 B/lane bursts,
//     4x float4) with register double-buffering (uA/uB/wA/wB) -- full-sector
//     consumption kills the L2 stream-front thrash behind R1's 635 MB FETCH
//     and gives ~4000-cycle prefetch distance.
//     Per-step all-to-all of 21 L values via padded LDS row (wave-sync).
//     Stores: ALL dirs label-major base[(b*21+s)*512^2 + p*512 + t]:
//       dir0 -> out (raw L); dir1 -> l1 (L-u); dir2/3 -> l2t/l3t (L-u,
//       TRANSPOSED planes). Staged in LDS 32-step windows, flushed as full
//       128-B-line wave stores (WRITE_SIZE exact 352 MB, verified R1).
//   finish: out += l1 + T(l2t) + T(l3t) via 32x33 LDS tiles.
// Path B fallback (small ws): sequential no-scratch kernels (unchanged).

#define DLBL 21
#define SP 512
#define NB 4
#define SPSP ((long)SP * SP)
#define NELEM ((long)NB * DLBL * SP * SP)   // 22,020,096 floats

// ---- transpose: u planes (0..83) + ewT overlay planes (84..91) ----
__global__ __launch_bounds__(256)
void transpose2_kernel(const float* __restrict__ u, const float* __restrict__ ew,
                       float* __restrict__ uT, float* l2t, float* l3t)
{
    __shared__ float tile[32][33];
    const int plane = blockIdx.z;
    const float* src;
    float* dst;
    if (plane < NB * DLBL) {
        src = u  + (long)plane * SPSP;
        dst = uT + (long)plane * SPSP;
    } else {
        const int q = plane - NB * DLBL;            // q = b*2 + (dir-2)
        const int b = q >> 1, db = q & 1;
        src = ew + (long)(b * 4 + 2 + db) * SPSP;
        dst = (db ? l3t : l2t) + (long)(b * DLBL + 20) * SPSP;  // overlay
    }
    const int x0 = blockIdx.x * 32, y0 = blockIdx.y * 32;
    const int tx = threadIdx.x & 31, ty = threadIdx.x >> 5;  // 32 x 8
#pragma unroll
    for (int j = 0; j < 4; ++j)
        tile[ty + 8 * j][tx] = src[(long)(y0 + ty + 8 * j) * SP + (x0 + tx)];
    __syncthreads();
#pragma unroll
    for (int j = 0; j < 4; ++j)
        dst[(long)(x0 + ty + 8 * j) * SP + (y0 + tx)] = tile[tx][ty + 8 * j];
}

// ---------------- main sweep (Path A, blocked streams) ----------------
__global__ __launch_bounds__(64, 3)
void sweep3(const float* __restrict__ unary, const float* __restrict__ ew,
            const float* __restrict__ Vmat, const float* __restrict__ uT,
            float* __restrict__ out, float* __restrict__ l1,
            float* l2t, float* l3t)
{
    __shared__ float xch[4][24];
    __shared__ float stage[4][693];      // [group][s*33 + (t&31)], +1 pad/row
    const int lane = threadIdx.x;
    const int g    = lane / DLBL;              // 0..2 (3 = idle lane 63)
    const int s    = lane - g * DLBL;
    int taskId = blockIdx.x * 3 + (g < 3 ? g : 0);
    if (taskId >= 8192) taskId = 8191;

    const int dir  = taskId >> 11;
    const int line = taskId & 2047;
    const int b    = line >> 9;
    const int p    = line & (SP - 1);          // h for axis 0, w for axis 1
    const int axis = dir >> 1;
    const int rev  = dir & 1;
    const float usub = (dir == 0) ? 0.0f : 1.0f;   // dirs 1-3 store L-u

    float Vc[DLBL];
#pragma unroll
    for (int j = 0; j < DLBL; ++j) Vc[j] = Vmat[j * DLBL + s];

    const float4* ub4 = (const float4*)((axis ? uT : unary)
                        + (long)(b * DLBL + s) * SPSP + (long)p * SP);
    // w stream: stride-1 everywhere. Vertical dirs read the ewT overlay
    // planes inside l2t/l3t (plane b*21+20), filled by transpose2.
    const float* wbase = axis
        ? ((dir == 2 ? l2t : l3t) + (long)(b * DLBL + 20) * SPSP + (long)p * SP)
        : (ew + (long)(b * 4 + dir) * SPSP + (long)p * SP);
    const float4* wb4 = (const float4*)wbase;

    const int frow = lane >> 5, fcol = lane & 31;
    const int stbase = s * 33;

    float4 uA[4], uB[4], wA[4], wB[4];
    float cur = 0.0f;

#define QIDX(bi, k) (rev ? (127 - 4 * (bi) - (k)) : (4 * (bi) + (k)))

#define LOADBLK(bi, U, W) do {                                              \
    _Pragma("unroll")                                                       \
    for (int k = 0; k < 4; ++k) {                                           \
        const int q_ = QIDX(bi, k);                                         \
        U[k] = ub4[q_]; W[k] = wb4[q_];                                     \
    } } while (0)

#define PROCESS(bi, U, W, FIRST) do {                                       \
    _Pragma("unroll")                                                       \
    for (int k = 0; k < 4; ++k) {                                           \
        const float ua_[4] = {U[k].x, U[k].y, U[k].z, U[k].w};              \
        const float wa_[4] = {W[k].x, W[k].y, W[k].z, W[k].w};              \
        const int q_ = QIDX(bi, k);                                         \
        _Pragma("unroll")                                                   \
        for (int j = 0; j < 4; ++j) {                                       \
            const int   jc  = rev ? 3 - j : j;                              \
            const float u_c = ua_[jc];                                      \
            const float w_c = wa_[jc];                                      \
            const int   t   = q_ * 4 + jc;                                  \
            xch[g][s] = cur;                                                \
            __builtin_amdgcn_wave_barrier();                                \
            float Lp[24];                                                   \
            _Pragma("unroll")                                               \
            for (int qq = 0; qq < 6; ++qq)                                  \
                ((float4*)Lp)[qq] = ((const float4*)(&xch[g][0]))[qq];      \
            __builtin_amdgcn_wave_barrier();                                \
            float c[DLBL];                                                  \
            _Pragma("unroll")                                               \
            for (int jj = 0; jj < DLBL; ++jj)                               \
                c[jj] = fmaf(w_c, Vc[jj], Lp[jj]);                          \
            float m7[7];                                                    \
            _Pragma("unroll")                                               \
            for (int kk = 0; kk < 7; ++kk)                                  \
                m7[kk] = fminf(fminf(c[3*kk], c[3*kk+1]), c[3*kk+2]);       \
            const float ma = fminf(fminf(m7[0], m7[1]), m7[2]);             \
            const float mb = fminf(fminf(m7[3], m7[4]), m7[5]);             \
            const float nv = u_c + fminf(fminf(ma, mb), m7[6]);             \
            cur = ((FIRST) && k == 0 && j == 0) ? u_c : nv;                 \
            stage[g][stbase + (t & 31)] = fmaf(-usub, u_c, cur);            \
        }                                                                   \
    } } while (0)

#define FLUSH(bi) do {                                                      \
    __builtin_amdgcn_wave_barrier();                                        \
    for (int gg = 0; gg < 3; ++gg) {                                        \
        const int tid = blockIdx.x * 3 + gg;                                \
        if (tid >= 8192) break;                                             \
        const int d_ = tid >> 11;                                           \
        const int ln = tid & 2047;                                          \
        const int bb = ln >> 9;                                             \
        const int pp = ln & (SP - 1);                                       \
        const int w0 = (d_ & 1) ? (496 - 16 * (bi)) : (16 * (bi) - 16);     \
        float* dst = (d_ == 0) ? out : (d_ == 1) ? l1                       \
                   : (d_ == 2) ? l2t : l3t;                                 \
        float* bp = dst + (long)(bb * DLBL) * SPSP + (long)pp * SP + w0     \
                        + (long)frow * SPSP;                                \
        _Pragma("unroll")                                                   \
        for (int r2 = 0; r2 < 11; ++r2) {                                   \
            const int rr = 2 * r2 + frow;                                   \
            if (rr < DLBL) bp[fcol] = stage[gg][rr * 33 + fcol];            \
            bp += 2 * SPSP;                                                 \
        }                                                                   \
    }                                                                       \
    __builtin_amdgcn_wave_barrier();                                        \
} while (0)

    LOADBLK(0, uA, wA);
    for (int m = 0; m < 16; ++m) {
        LOADBLK(2 * m + 1, uB, wB);        // prefetch odd block
        PROCESS(2 * m, uA, wA, (m == 0));
        if (m < 15) LOADBLK(2 * m + 2, uA, wA);   // prefetch next even block
        PROCESS(2 * m + 1, uB, wB, false);
        FLUSH(2 * m + 1);                  // 32-step window complete
    }

#undef QIDX
#undef LOADBLK
#undef PROCESS
#undef FLUSH
}

// ---------------- finish: out += l1 + T(l2t) + T(l3t) ----------------
__global__ __launch_bounds__(256)
void finish_kernel(const float* __restrict__ l1, const float* __restrict__ l2t,
                   const float* __restrict__ l3t, float* __restrict__ out)
{
    __shared__ float t2[32][33], t3[32][33];
    const long pb = (long)blockIdx.z * SPSP;
    const int x0 = blockIdx.x * 32, y0 = blockIdx.y * 32;
    const int tx = threadIdx.x & 31, ty = threadIdx.x >> 5;
#pragma unroll
    for (int j = 0; j < 4; ++j) {
        const long o = pb + (long)(x0 + ty + 8 * j) * SP + (y0 + tx);
        t2[ty + 8 * j][tx] = l2t[o];
        t3[ty + 8 * j][tx] = l3t[o];
    }
    __syncthreads();
#pragma unroll
    for (int j = 0; j < 4; ++j) {
        const long o = pb + (long)(y0 + ty + 8 * j) * SP + (x0 + tx);
        out[o] = out[o] + l1[o] + t2[tx][ty + 8 * j] + t3[tx][ty + 8 * j];
    }
}

// ---------------- fallback (Path B): no-scratch sequential sweeps ----------
template<int MODE>   // 1: dir0 store L to out; 2: out += L - u
__global__ __launch_bounds__(64)
void sweep_fb(const float* __restrict__ unary, const float* __restrict__ ew,
              const float* __restrict__ Vmat, float* __restrict__ out,
              int taskBase)
{
    __shared__ float xch[4][24];
    const int lane = threadIdx.x;
    const int g    = lane / DLBL;
    const int s    = lane - g * DLBL;
    int local = blockIdx.x * 3 + (g < 3 ? g : 0);
    const bool valid = (g < 3) && (local < 2048);
    if (local >= 2048) local = 2047;
    const int taskId = taskBase + local;
    const int dir  = taskId >> 11;
    const int line = taskId & 2047;
    const int b = line >> 9, p = line & (SP - 1);
    const int axis = dir >> 1, rev = dir & 1;

    float Vc[DLBL];
#pragma unroll
    for (int j = 0; j < DLBL; ++j) Vc[j] = Vmat[j * DLBL + s];

    const long ustep = axis ? SP : 1;
    const long ubase = (long)(b * DLBL + s) * SPSP + (axis ? (long)p : (long)p * SP);
    const long wbase = (long)(b * 4 + dir) * SPSP + (axis ? (long)p : (long)p * SP);
    const long uoff  = rev ? -ustep : ustep;
    const long ust   = rev ? (long)(SP - 1) * ustep : 0;

    const float* up = unary + ubase + ust;
    const float* wp = ew    + wbase + ust;
    float*       op = out   + ubase + ust;

    float cur = up[0];
    if (valid && MODE == 1) *op = cur;

    float ub0 = up[uoff], ub1 = up[2*uoff], ub2 = up[3*uoff], ub3 = up[4*uoff];
    float wb0 = wp[uoff], wb1 = wp[2*uoff], wb2 = wp[3*uoff], wb3 = wp[4*uoff];
    float ob0 = 0, ob1 = 0, ob2 = 0, ob3 = 0;
    if (MODE == 2) { ob0 = op[uoff]; ob1 = op[2*uoff]; ob2 = op[3*uoff]; ob3 = op[4*uoff]; }
    const float* upf = up + 4 * uoff;
    const float* wpf = wp + 4 * uoff;
    const float* opf = op + 4 * uoff;

    for (int t = 1; t < SP; ++t) {
        const float u_c = ub0, w_c = wb0, o_c = ob0;
        ub0 = ub1; ub1 = ub2; ub2 = ub3;
        wb0 = wb1; wb1 = wb2; wb2 = wb3;
        if (MODE == 2) { ob0 = ob1; ob1 = ob2; ob2 = ob3; }
        const bool adv = (t + 4) < SP;
        upf += adv ? uoff : 0; wpf += adv ? uoff : 0;
        ub3 = *upf; wb3 = *wpf;
        if (MODE == 2) { opf += adv ? uoff : 0; ob3 = *opf; }

        xch[g][s] = cur;
        __builtin_amdgcn_wave_barrier();
        float Lp[24];
#pragma unroll
        for (int q = 0; q < 6; ++q)
            ((float4*)Lp)[q] = ((const float4*)(&xch[g][0]))[q];
        __builtin_amdgcn_wave_barrier();

        float c[DLBL];
#pragma unroll
        for (int j = 0; j < DLBL; ++j) c[j] = fmaf(w_c, Vc[j], Lp[j]);
        float m7[7];
#pragma unroll
        for (int k = 0; k < 7; ++k)
            m7[k] = fminf(fminf(c[3*k], c[3*k+1]), c[3*k+2]);
        const float ma = fminf(fminf(m7[0], m7[1]), m7[2]);
        const float mb = fminf(fminf(m7[3], m7[4]), m7[5]);
        cur = u_c + fminf(fminf(ma, mb), m7[6]);

        op += uoff;
        if (valid) *op = (MODE == 2) ? (o_c + cur - u_c) : cur;
    }
}

extern "C" void kernel_launch(void* const* d_in, const int* in_sizes, int n_in,
                              void* d_out, int out_size, void* d_ws, size_t ws_size,
                              hipStream_t stream) {
    const float* unary = (const float*)d_in[0];   // (4,1,21,512,512) f32
    const float* ew    = (const float*)d_in[1];   // (4,4,512,512)   f32
    const float* Vmat  = (const float*)d_in[2];   // (21,21)         f32
    float* o = (float*)d_out;

    const size_t needA = (size_t)(4 * NELEM) * sizeof(float);   // 352,321,536 B

    if (ws_size >= needA) {
        float* uT  = (float*)d_ws;
        float* l1  = uT + NELEM;
        float* l2t = l1 + NELEM;
        float* l3t = l2t + NELEM;

        dim3 tg(16, 16, NB * DLBL + 8);           // +8 ewT overlay planes
        transpose2_kernel<<<tg, 256, 0, stream>>>(unary, ew, uT, l2t, l3t);

        const int grid = (8192 + 2) / 3;          // 2731
        sweep3<<<grid, 64, 0, stream>>>(unary, ew, Vmat, uT,
                                        o, l1, l2t, l3t);

        finish_kernel<<<dim3(16, 16, NB * DLBL), 256, 0, stream>>>(l1, l2t, l3t, o);
    } else {
        const int grid = (2048 + 2) / 3;          // 683
        sweep_fb<1><<<grid, 64, 0, stream>>>(unary, ew, Vmat, o, 0);
        for (int d = 1; d < 4; ++d)
            sweep_fb<2><<<grid, 64, 0, stream>>>(unary, ew, Vmat, o, d * 2048);
    }
}